// Round 5
// baseline (330.755 us; speedup 1.0000x reference)
//
#include <hip/hip_runtime.h>
#include <math.h>

#define BATCH 4
#define SEQ 2048
#define DMODEL 1024
#define NHEAD 16
#define DHEAD 64
#define MTOT (BATCH * SEQ)   /* 8192 */
#define LN_EPS 1e-5f

typedef float f4 __attribute__((ext_vector_type(4)));
typedef float f32x4 __attribute__((ext_vector_type(4)));
typedef __bf16 bf16_t;
typedef __bf16 bf16x8 __attribute__((ext_vector_type(8)));
typedef __bf16 bf16x4 __attribute__((ext_vector_type(4)));

// async global->LDS, 16B per lane; dest = wave-uniform base + lane*16
__device__ __forceinline__ void gload_lds16(const bf16_t* g, bf16_t* l) {
    __builtin_amdgcn_global_load_lds(
        (const __attribute__((address_space(1))) void*)g,
        (__attribute__((address_space(3))) void*)l, 16, 0, 0);
}

// ---------------------------------------------------------------------------
// fp32 -> bf16 elementwise (n4 = count of float4 groups)
// ---------------------------------------------------------------------------
__global__ __launch_bounds__(256) void cvt_bf16(
    const float* __restrict__ x, bf16_t* __restrict__ y, int n4)
{
    for (int i = blockIdx.x * 256 + threadIdx.x; i < n4; i += gridDim.x * 256) {
        f4 v = *(const f4*)&x[(size_t)i * 4];
        bf16x4 o;
        o[0] = (bf16_t)v[0]; o[1] = (bf16_t)v[1];
        o[2] = (bf16_t)v[2]; o[3] = (bf16_t)v[3];
        *(bf16x4*)&y[(size_t)i * 4] = o;
    }
}

// ---------------------------------------------------------------------------
// W[k][n] fp32 -> Wt[n][k] bf16 (32x32 LDS tiles)
// ---------------------------------------------------------------------------
__global__ __launch_bounds__(256) void wtrans(
    const float* __restrict__ W, bf16_t* __restrict__ Wt)
{
    __shared__ float tile[32][33];
    const int n0 = blockIdx.x * 32, k0 = blockIdx.y * 32;
    const int c = threadIdx.x & 31, rr = threadIdx.x >> 5;   // 8 rows/pass
#pragma unroll
    for (int i = 0; i < 32; i += 8)
        tile[rr + i][c] = W[(size_t)(k0 + rr + i) * DMODEL + n0 + c];
    __syncthreads();
#pragma unroll
    for (int i = 0; i < 32; i += 8)
        Wt[(size_t)(n0 + rr + i) * DMODEL + k0 + c] = (bf16_t)tile[c][rr + i];
}

// ---------------------------------------------------------------------------
// bf16 MFMA GEMM: C[M=8192][1024] = A[M][1024] @ Bt[n][k]^T + bias
// 128x128 tile, BK=32, 4 waves (2x2), 16x16x32 MFMA, global_load_lds(16B)
// LDS swizzle: byte ^= ((byte>>7)&3)<<4 (read side); source pre-swizzled.
// ---------------------------------------------------------------------------
template<int OUT_BF16>
__global__ __launch_bounds__(256) void gemm_mfma(
    const bf16_t* __restrict__ A, const bf16_t* __restrict__ Bt,
    const float* __restrict__ bias, void* __restrict__ Cout)
{
    __shared__ bf16_t As[128 * 32];
    __shared__ bf16_t Bs[128 * 32];
    const int t = threadIdx.x;
    const int w = t >> 6, lane = t & 63;
    const int r16 = lane & 15, g = lane >> 4;
    const int m0 = blockIdx.y * 128, n0 = blockIdx.x * 128;
    const int wr = w >> 1, wc = w & 1;

    // staging: issue r in {0,1}: dest byte y = r*4096 + w*1024 + lane*16
    const int y0 = w * 1024 + lane * 16;
    const int y1 = y0 + 4096;
    const int row0 = y0 >> 6, row1 = y1 >> 6;
    const int sl0 = ((y0 >> 4) & 3) ^ ((row0 >> 1) & 3);
    const int sl1 = ((y1 >> 4) & 3) ^ ((row1 >> 1) & 3);
    const bf16_t* a0 = A + (size_t)(m0 + row0) * DMODEL + sl0 * 8;
    const bf16_t* a1 = A + (size_t)(m0 + row1) * DMODEL + sl1 * 8;
    const bf16_t* b0 = Bt + (size_t)(n0 + row0) * DMODEL + sl0 * 8;
    const bf16_t* b1 = Bt + (size_t)(n0 + row1) * DMODEL + sl1 * 8;
    bf16_t* da0 = As + w * 512;
    bf16_t* da1 = As + 2048 + w * 512;
    bf16_t* db0 = Bs + w * 512;
    bf16_t* db1 = Bs + 2048 + w * 512;

    // fragment read offsets (elements), swizzled
    int aoff[4], boff[4];
#pragma unroll
    for (int i = 0; i < 4; ++i) {
        int ar = wr * 64 + i * 16 + r16;
        int al = ar * 64 + g * 16;
        al ^= ((ar >> 1) & 3) << 4;
        aoff[i] = al >> 1;
        int br = wc * 64 + i * 16 + r16;
        int bl = br * 64 + g * 16;
        bl ^= ((br >> 1) & 3) << 4;
        boff[i] = bl >> 1;
    }

    const f32x4 z4 = {0.f, 0.f, 0.f, 0.f};
    f32x4 acc[4][4];
#pragma unroll
    for (int i = 0; i < 4; ++i)
#pragma unroll
        for (int j = 0; j < 4; ++j) acc[i][j] = z4;

    for (int k0 = 0; k0 < DMODEL; k0 += 32) {
        __syncthreads();                 // prior LDS reads complete
        gload_lds16(a0 + k0, da0);
        gload_lds16(a1 + k0, da1);
        gload_lds16(b0 + k0, db0);
        gload_lds16(b1 + k0, db1);
        __syncthreads();                 // barrier drains vmcnt -> tiles ready
        bf16x8 af[4], bfr[4];
#pragma unroll
        for (int i = 0; i < 4; ++i) af[i] = *(const bf16x8*)&As[aoff[i]];
#pragma unroll
        for (int j = 0; j < 4; ++j) bfr[j] = *(const bf16x8*)&Bs[boff[j]];
#pragma unroll
        for (int i = 0; i < 4; ++i)
#pragma unroll
            for (int j = 0; j < 4; ++j)
                acc[i][j] = __builtin_amdgcn_mfma_f32_16x16x32_bf16(
                    af[i], bfr[j], acc[i][j], 0, 0, 0);
    }

    // epilogue: D row = (lane>>4)*4 + reg, col = lane&15  (m89-verified)
#pragma unroll
    for (int j = 0; j < 4; ++j) {
        const int col = n0 + wc * 64 + j * 16 + r16;
        const float bv = bias[col];
#pragma unroll
        for (int i = 0; i < 4; ++i) {
            const int rbase = m0 + wr * 64 + i * 16 + g * 4;
#pragma unroll
            for (int rr = 0; rr < 4; ++rr) {
                float vv = acc[i][j][rr] + bv;
                if (OUT_BF16)
                    ((bf16_t*)Cout)[(size_t)(rbase + rr) * DMODEL + col] = (bf16_t)vv;
                else
                    ((float*)Cout)[(size_t)(rbase + rr) * DMODEL + col] = vv;
            }
        }
    }
}

// ---------------------------------------------------------------------------
// MFMA flash attention, swapped-QK^T + in-register base-2 softmax + defer-max
// + double-buffered K/V pipeline with raw barriers (no vmcnt drain).
//
// Pipeline per step t (cur = t&1):
//   A: Vt[cur] transpose-writes from vcur regs (compiler's vmcnt wait here
//      FIFO-drains the K(t) gload_lds issued last iteration)
//   B: issue gload_lds K(t+1) -> Ks[cur^1];  C: issue V(t+1) -> vnxt regs
//   lgkmcnt(0); s_barrier           (vmcnt NOT drained -> prefetch in flight)
//   QK^T from Ks[cur]; softmax; Ps writes
//   lgkmcnt(0); s_barrier
//   PV from Ps, Vt[cur]; vcur = vnxt
// Hazards: Ks[cur^1] restage (B of t+1) happens only after all waves passed
// the 2nd barrier of t, by which their QK^T reads of t completed (lgkm wait
// precedes MFMA use). Vt/Ks buffers alternate; Ps write->read and read->write
// are separated by the two barriers. Cross-wave K visibility: each wave's own
// vmcnt wait at A precedes barrier 1.
// ---------------------------------------------------------------------------
__global__ __launch_bounds__(256) void flash_mfma(
    const bf16_t* __restrict__ qg, const bf16_t* __restrict__ kg,
    const bf16_t* __restrict__ vg, bf16_t* __restrict__ ctx)
{
    __shared__ bf16_t Ks[2][64 * 64];   // [key][dim], byte ^= (key&7)<<4
    __shared__ bf16_t Vt[2][64 * 72];   // [dim][key], padded pitch 72
    __shared__ bf16_t Ps[64 * 72];      // [q][key],  padded pitch 72

    const int t = threadIdx.x;
    const int w = t >> 6, lane = t & 63;
    const int r16 = lane & 15, g = lane >> 4;
    const int g4 = g * 4;
    const int q0 = blockIdx.x * 64, h = blockIdx.y, b = blockIdx.z;

    // Q fragments in registers: row = q0+16w+r16, k = kc*32 + g*8 + j
    bf16x8 qf0, qf1;
    {
        const bf16_t* qrow = qg + (size_t)(b * SEQ + q0 + 16 * w + r16) * DMODEL + h * DHEAD;
        qf0 = *(const bf16x8*)&qrow[g * 8];
        qf1 = *(const bf16x8*)&qrow[32 + g * 8];
    }

    // K staging: issue r: dest byte y = r*4096 + w*1024 + lane*16
    const int yk0 = w * 1024 + lane * 16;
    const int yk1 = yk0 + 4096;
    const int kr0 = yk0 >> 7, kr1 = yk1 >> 7;
    const int ks0 = ((yk0 >> 4) & 7) ^ (kr0 & 7);
    const int ks1 = ((yk1 >> 4) & 7) ^ (kr1 & 7);
    const bf16_t* kb0 = kg + (size_t)(b * SEQ + kr0) * DMODEL + h * DHEAD + ks0 * 8;
    const bf16_t* kb1 = kg + (size_t)(b * SEQ + kr1) * DMODEL + h * DHEAD + ks1 * 8;
    const int kdo0 = w * 512;            // element offsets inside a Ks buffer
    const int kdo1 = 2048 + w * 512;

    // V staging: this thread loads key=lane, dims [w*16, w*16+16)
    const bf16_t* vb = vg + (size_t)(b * SEQ + lane) * DMODEL + h * DHEAD + w * 16;

    // K fragment offsets (elements), swizzled
    int koff[4][2];
#pragma unroll
    for (int nj = 0; nj < 4; ++nj) {
        const int key = nj * 16 + r16;
#pragma unroll
        for (int kc = 0; kc < 2; ++kc) {
            int lin = key * 128 + kc * 64 + g * 16;
            lin ^= (key & 7) << 4;
            koff[nj][kc] = lin >> 1;
        }
    }

    const f32x4 z4 = {0.f, 0.f, 0.f, 0.f};
    // softmax state per lane: q-row = r16 of this wave, base-2 domain
    float m2 = -1e30f, l2 = 0.f;
    f32x4 o_[4];                       // [dv-block]; rows = q = g*4+rr
#pragma unroll
    for (int i = 0; i < 4; ++i) o_[i] = z4;

    const float C2 = 0.1803368801f;    // (1/8) * log2(e)
    const float THR2 = 11.5416f;       // 8 * log2(e)

    // ---- prologue: stage tile 0
    gload_lds16(kb0, &Ks[0][kdo0]);
    gload_lds16(kb1, &Ks[0][kdo1]);
    bf16x8 vcur0 = *(const bf16x8*)&vb[0];
    bf16x8 vcur1 = *(const bf16x8*)&vb[8];
    bf16x8 vnxt0 = vcur0, vnxt1 = vcur1;

    for (int kv0 = 0; kv0 < SEQ; kv0 += 64) {
        const int cur = (kv0 >> 6) & 1, nxt = cur ^ 1;

        // A: V transpose-write (compiler vmcnt-waits vcur here -> K(t) drained)
#pragma unroll
        for (int e = 0; e < 8; ++e) {
            Vt[cur][(w * 16 + e) * 72 + lane]     = vcur0[e];
            Vt[cur][(w * 16 + 8 + e) * 72 + lane] = vcur1[e];
        }
        // B,C: prefetch tile t+1 (stays in flight across the barriers)
        if (kv0 + 64 < SEQ) {
            gload_lds16(kb0 + (size_t)(kv0 + 64) * DMODEL, &Ks[nxt][kdo0]);
            gload_lds16(kb1 + (size_t)(kv0 + 64) * DMODEL, &Ks[nxt][kdo1]);
            const bf16_t* vv = vb + (size_t)(kv0 + 64) * DMODEL;
            vnxt0 = *(const bf16x8*)&vv[0];
            vnxt1 = *(const bf16x8*)&vv[8];
        }
        asm volatile("s_waitcnt lgkmcnt(0)" ::: "memory");
        __builtin_amdgcn_s_barrier();

        // S^T = K Q^T : s[nj][rr] = S[key = nj*16+g*4+rr][q = 16w+r16]
        f32x4 s[4];
        __builtin_amdgcn_s_setprio(1);
#pragma unroll
        for (int nj = 0; nj < 4; ++nj) {
            bf16x8 kf0 = *(const bf16x8*)&Ks[cur][koff[nj][0]];
            bf16x8 kf1 = *(const bf16x8*)&Ks[cur][koff[nj][1]];
            s[nj] = __builtin_amdgcn_mfma_f32_16x16x32_bf16(kf0, qf0, z4, 0, 0, 0);
            s[nj] = __builtin_amdgcn_mfma_f32_16x16x32_bf16(kf1, qf1, s[nj], 0, 0, 0);
        }
        __builtin_amdgcn_s_setprio(0);

        // row max over this lane's 16 scores (one q-row) + reduce over g
        float mm[4];
#pragma unroll
        for (int nj = 0; nj < 4; ++nj)
            mm[nj] = fmaxf(fmaxf(s[nj][0], s[nj][1]), fmaxf(s[nj][2], s[nj][3]));
        float mx2 = fmaxf(fmaxf(mm[0], mm[1]), fmaxf(mm[2], mm[3])) * C2;
        mx2 = fmaxf(mx2, __shfl_xor(mx2, 16));
        mx2 = fmaxf(mx2, __shfl_xor(mx2, 32));

        // defer-max: rescale only when the max moved by > 8 (nat-log units)
        if (!__all(mx2 - m2 <= THR2)) {
            const float mnew = fmaxf(m2, mx2);
            const float fs = exp2f(m2 - mnew);
            m2 = mnew;
            l2 *= fs;
            const float f0 = __shfl(fs, g4 + 0, 16);
            const float f1 = __shfl(fs, g4 + 1, 16);
            const float f2 = __shfl(fs, g4 + 2, 16);
            const float f3 = __shfl(fs, g4 + 3, 16);
#pragma unroll
            for (int nj = 0; nj < 4; ++nj) {
                f32x4 t4 = o_[nj];
                t4[0] *= f0; t4[1] *= f1; t4[2] *= f2; t4[3] *= f3;
                o_[nj] = t4;
            }
        }

        // P = exp2(s*C2 - m2), row-sum in-register + 2 shfl
        float p[4][4];
        float rs = 0.f;
#pragma unroll
        for (int nj = 0; nj < 4; ++nj)
#pragma unroll
            for (int rr = 0; rr < 4; ++rr) {
                p[nj][rr] = exp2f(s[nj][rr] * C2 - m2);
                rs += p[nj][rr];
            }
        rs += __shfl_xor(rs, 16);
        rs += __shfl_xor(rs, 32);
        l2 += rs;

        // pack 4 consecutive keys -> b64 write: Ps[q=16w+r16][nj*16+g4 ..]
#pragma unroll
        for (int nj = 0; nj < 4; ++nj) {
            bf16x4 pk;
            pk[0] = (bf16_t)p[nj][0]; pk[1] = (bf16_t)p[nj][1];
            pk[2] = (bf16_t)p[nj][2]; pk[3] = (bf16_t)p[nj][3];
            *(bf16x4*)&Ps[(16 * w + r16) * 72 + nj * 16 + g4] = pk;
        }
        asm volatile("s_waitcnt lgkmcnt(0)" ::: "memory");
        __builtin_amdgcn_s_barrier();

        // O += P V : A-frag from Ps, B-frag from Vt[cur]
        bf16x8 pf0 = *(const bf16x8*)&Ps[(16 * w + r16) * 72 + g * 8];
        bf16x8 pf1 = *(const bf16x8*)&Ps[(16 * w + r16) * 72 + 32 + g * 8];
        __builtin_amdgcn_s_setprio(1);
#pragma unroll
        for (int nj = 0; nj < 4; ++nj) {
            bf16x8 vf0 = *(const bf16x8*)&Vt[cur][(nj * 16 + r16) * 72 + g * 8];
            bf16x8 vf1 = *(const bf16x8*)&Vt[cur][(nj * 16 + r16) * 72 + 32 + g * 8];
            o_[nj] = __builtin_amdgcn_mfma_f32_16x16x32_bf16(pf0, vf0, o_[nj], 0, 0, 0);
            o_[nj] = __builtin_amdgcn_mfma_f32_16x16x32_bf16(pf1, vf1, o_[nj], 0, 0, 0);
        }
        __builtin_amdgcn_s_setprio(0);

        vcur0 = vnxt0; vcur1 = vnxt1;
    }

    // write context (bf16): o_ rows are q = g*4+rr; l lives at lane q=r16
#pragma unroll
    for (int rr = 0; rr < 4; ++rr) {
        const float lv = __shfl(l2, g4 + rr, 16);
        const float inv = 1.0f / lv;
        const size_t rowbase =
            (size_t)(b * SEQ + q0 + 16 * w + g4 + rr) * DMODEL + h * DHEAD;
#pragma unroll
        for (int nj = 0; nj < 4; ++nj)
            ctx[rowbase + nj * 16 + r16] = (bf16_t)(o_[nj][rr] * inv);
    }
}

// ---------------------------------------------------------------------------
// out = LayerNorm(x + res) * g + b, rows of 1024. One block per row.
// ---------------------------------------------------------------------------
__global__ __launch_bounds__(256) void ln_residual(
    const float* __restrict__ x, const float* __restrict__ res,
    const float* __restrict__ g, const float* __restrict__ bb,
    float* __restrict__ out)
{
    const int row = blockIdx.x;
    const int t = threadIdx.x;
    f4 xv = *(const f4*)&x[(size_t)row * DMODEL + t * 4];
    f4 rv = *(const f4*)&res[(size_t)row * DMODEL + t * 4];
    f4 v;
#pragma unroll
    for (int u = 0; u < 4; ++u) v[u] = xv[u] + rv[u];

    float s = 0.f, s2 = 0.f;
#pragma unroll
    for (int u = 0; u < 4; ++u) { s += v[u]; s2 += v[u] * v[u]; }
#pragma unroll
    for (int off = 1; off < 64; off <<= 1) {
        s  += __shfl_xor(s, off);
        s2 += __shfl_xor(s2, off);
    }
    __shared__ float red[2][4];
    const int wid = t >> 6, lane = t & 63;
    if (lane == 0) { red[0][wid] = s; red[1][wid] = s2; }
    __syncthreads();
    s  = red[0][0] + red[0][1] + red[0][2] + red[0][3];
    s2 = red[1][0] + red[1][1] + red[1][2] + red[1][3];

    const float mean = s * (1.0f / DMODEL);
    const float var  = s2 * (1.0f / DMODEL) - mean * mean;
    const float rstd = rsqrtf(var + LN_EPS);

    f4 gv = *(const f4*)&g[t * 4];
    f4 bv = *(const f4*)&bb[t * 4];
    f4 ov;
#pragma unroll
    for (int u = 0; u < 4; ++u) ov[u] = (v[u] - mean) * rstd * gv[u] + bv[u];
    *(f4*)&out[(size_t)row * DMODEL + t * 4] = ov;
}

// ---------------------------------------------------------------------------
extern "C" void kernel_launch(void* const* d_in, const int* in_sizes, int n_in,
                              void* d_out, int out_size, void* d_ws, size_t ws_size,
                              hipStream_t stream)
{
    const float* Q   = (const float*)d_in[0];
    const float* Wq  = (const float*)d_in[1];
    const float* bq  = (const float*)d_in[2];
    const float* Wk  = (const float*)d_in[3];
    const float* bk  = (const float*)d_in[4];
    const float* Wv  = (const float*)d_in[5];
    const float* bv  = (const float*)d_in[6];
    const float* Wo  = (const float*)d_in[7];
    const float* bo  = (const float*)d_in[8];
    const float* lng = (const float*)d_in[9];
    const float* lnb = (const float*)d_in[10];

    char* wsb = (char*)d_ws;
    // 0..16M: Qbf | 16..32M: q/ctx | 32..48M: k | 48..64M: v
    // 32..64M (after attn): attn_out fp32 | 64..72M: transposed bf16 weights
    bf16_t* Qbf  = (bf16_t*)(wsb);
    bf16_t* qb   = (bf16_t*)(wsb + (size_t)(16 << 20));
    bf16_t* kb   = (bf16_t*)(wsb + (size_t)(32 << 20));
    bf16_t* vbuf = (bf16_t*)(wsb + (size_t)(48 << 20));
    float*  ao   = (float*) (wsb + (size_t)(32 << 20));
    bf16_t* Wqt  = (bf16_t*)(wsb + (size_t)(64 << 20));
    bf16_t* Wkt  = (bf16_t*)(wsb + (size_t)(66 << 20));
    bf16_t* Wvt  = (bf16_t*)(wsb + (size_t)(68 << 20));
    bf16_t* Wot  = (bf16_t*)(wsb + (size_t)(70 << 20));

    cvt_bf16<<<2048, 256, 0, stream>>>(Q, Qbf, MTOT * DMODEL / 4);
    dim3 wg(32, 32);
    wtrans<<<wg, 256, 0, stream>>>(Wq, Wqt);
    wtrans<<<wg, 256, 0, stream>>>(Wk, Wkt);
    wtrans<<<wg, 256, 0, stream>>>(Wv, Wvt);
    wtrans<<<wg, 256, 0, stream>>>(Wo, Wot);

    dim3 gg(DMODEL / 128, MTOT / 128);            // (8, 64)
    gemm_mfma<1><<<gg, 256, 0, stream>>>(Qbf, Wqt, bq, qb);
    gemm_mfma<1><<<gg, 256, 0, stream>>>(Qbf, Wkt, bk, kb);
    gemm_mfma<1><<<gg, 256, 0, stream>>>(Qbf, Wvt, bv, vbuf);

    dim3 ga(SEQ / 64, NHEAD, BATCH);              // (32, 16, 4)
    flash_mfma<<<ga, 256, 0, stream>>>(qb, kb, vbuf, qb);  // ctx aliases q

    gemm_mfma<0><<<gg, 256, 0, stream>>>(qb, Wot, bo, ao);

    ln_residual<<<MTOT, 256, 0, stream>>>(ao, Q, lng, lnb, (float*)d_out);
}

// Round 6
// 283.272 us; speedup vs baseline: 1.1676x; 1.1676x over previous
//
#include <hip/hip_runtime.h>
#include <math.h>

#define BATCH 4
#define SEQ 2048
#define DMODEL 1024
#define NHEAD 16
#define DHEAD 64
#define MTOT (BATCH * SEQ)   /* 8192 */
#define LN_EPS 1e-5f

typedef float f4 __attribute__((ext_vector_type(4)));
typedef float f32x4 __attribute__((ext_vector_type(4)));
typedef __bf16 bf16_t;
typedef __bf16 bf16x8 __attribute__((ext_vector_type(8)));
typedef __bf16 bf16x4 __attribute__((ext_vector_type(4)));

// async global->LDS, 16B per lane; dest = wave-uniform base + lane*16
__device__ __forceinline__ void gload_lds16(const bf16_t* g, bf16_t* l) {
    __builtin_amdgcn_global_load_lds(
        (const __attribute__((address_space(1))) void*)g,
        (__attribute__((address_space(3))) void*)l, 16, 0, 0);
}

// ---------------------------------------------------------------------------
// fp32 -> bf16 elementwise (n4 = count of float4 groups)
// ---------------------------------------------------------------------------
__global__ __launch_bounds__(256) void cvt_bf16(
    const float* __restrict__ x, bf16_t* __restrict__ y, int n4)
{
    for (int i = blockIdx.x * 256 + threadIdx.x; i < n4; i += gridDim.x * 256) {
        f4 v = *(const f4*)&x[(size_t)i * 4];
        bf16x4 o;
        o[0] = (bf16_t)v[0]; o[1] = (bf16_t)v[1];
        o[2] = (bf16_t)v[2]; o[3] = (bf16_t)v[3];
        *(bf16x4*)&y[(size_t)i * 4] = o;
    }
}

// ---------------------------------------------------------------------------
// W[k][n] fp32 -> Wt[n][k] bf16 (32x32 LDS tiles)
// ---------------------------------------------------------------------------
__global__ __launch_bounds__(256) void wtrans(
    const float* __restrict__ W, bf16_t* __restrict__ Wt)
{
    __shared__ float tile[32][33];
    const int n0 = blockIdx.x * 32, k0 = blockIdx.y * 32;
    const int c = threadIdx.x & 31, rr = threadIdx.x >> 5;   // 8 rows/pass
#pragma unroll
    for (int i = 0; i < 32; i += 8)
        tile[rr + i][c] = W[(size_t)(k0 + rr + i) * DMODEL + n0 + c];
    __syncthreads();
#pragma unroll
    for (int i = 0; i < 32; i += 8)
        Wt[(size_t)(n0 + rr + i) * DMODEL + k0 + c] = (bf16_t)tile[c][rr + i];
}

// ---------------------------------------------------------------------------
// bf16 MFMA GEMM: C[M=8192][1024] = A[M][1024] @ Bt[n][k]^T + bias
// 128x128 tile, BK=32, 4 waves (2x2), 16x16x32 MFMA, global_load_lds(16B)
// LDS swizzle: byte ^= ((byte>>7)&3)<<4 (read side); source pre-swizzled.
// ---------------------------------------------------------------------------
template<int OUT_BF16>
__global__ __launch_bounds__(256) void gemm_mfma(
    const bf16_t* __restrict__ A, const bf16_t* __restrict__ Bt,
    const float* __restrict__ bias, void* __restrict__ Cout)
{
    __shared__ bf16_t As[128 * 32];
    __shared__ bf16_t Bs[128 * 32];
    const int t = threadIdx.x;
    const int w = t >> 6, lane = t & 63;
    const int r16 = lane & 15, g = lane >> 4;
    const int m0 = blockIdx.y * 128, n0 = blockIdx.x * 128;
    const int wr = w >> 1, wc = w & 1;

    // staging: issue r in {0,1}: dest byte y = r*4096 + w*1024 + lane*16
    const int y0 = w * 1024 + lane * 16;
    const int y1 = y0 + 4096;
    const int row0 = y0 >> 6, row1 = y1 >> 6;
    const int sl0 = ((y0 >> 4) & 3) ^ ((row0 >> 1) & 3);
    const int sl1 = ((y1 >> 4) & 3) ^ ((row1 >> 1) & 3);
    const bf16_t* a0 = A + (size_t)(m0 + row0) * DMODEL + sl0 * 8;
    const bf16_t* a1 = A + (size_t)(m0 + row1) * DMODEL + sl1 * 8;
    const bf16_t* b0 = Bt + (size_t)(n0 + row0) * DMODEL + sl0 * 8;
    const bf16_t* b1 = Bt + (size_t)(n0 + row1) * DMODEL + sl1 * 8;
    bf16_t* da0 = As + w * 512;
    bf16_t* da1 = As + 2048 + w * 512;
    bf16_t* db0 = Bs + w * 512;
    bf16_t* db1 = Bs + 2048 + w * 512;

    // fragment read offsets (elements), swizzled
    int aoff[4], boff[4];
#pragma unroll
    for (int i = 0; i < 4; ++i) {
        int ar = wr * 64 + i * 16 + r16;
        int al = ar * 64 + g * 16;
        al ^= ((ar >> 1) & 3) << 4;
        aoff[i] = al >> 1;
        int br = wc * 64 + i * 16 + r16;
        int bl = br * 64 + g * 16;
        bl ^= ((br >> 1) & 3) << 4;
        boff[i] = bl >> 1;
    }

    const f32x4 z4 = {0.f, 0.f, 0.f, 0.f};
    f32x4 acc[4][4];
#pragma unroll
    for (int i = 0; i < 4; ++i)
#pragma unroll
        for (int j = 0; j < 4; ++j) acc[i][j] = z4;

    for (int k0 = 0; k0 < DMODEL; k0 += 32) {
        __syncthreads();                 // prior LDS reads complete
        gload_lds16(a0 + k0, da0);
        gload_lds16(a1 + k0, da1);
        gload_lds16(b0 + k0, db0);
        gload_lds16(b1 + k0, db1);
        __syncthreads();                 // barrier drains vmcnt -> tiles ready
        bf16x8 af[4], bfr[4];
#pragma unroll
        for (int i = 0; i < 4; ++i) af[i] = *(const bf16x8*)&As[aoff[i]];
#pragma unroll
        for (int j = 0; j < 4; ++j) bfr[j] = *(const bf16x8*)&Bs[boff[j]];
#pragma unroll
        for (int i = 0; i < 4; ++i)
#pragma unroll
            for (int j = 0; j < 4; ++j)
                acc[i][j] = __builtin_amdgcn_mfma_f32_16x16x32_bf16(
                    af[i], bfr[j], acc[i][j], 0, 0, 0);
    }

    // epilogue: D row = (lane>>4)*4 + reg, col = lane&15  (m89-verified)
#pragma unroll
    for (int j = 0; j < 4; ++j) {
        const int col = n0 + wc * 64 + j * 16 + r16;
        const float bv = bias[col];
#pragma unroll
        for (int i = 0; i < 4; ++i) {
            const int rbase = m0 + wr * 64 + i * 16 + g * 4;
#pragma unroll
            for (int rr = 0; rr < 4; ++rr) {
                float vv = acc[i][j][rr] + bv;
                if (OUT_BF16)
                    ((bf16_t*)Cout)[(size_t)(rbase + rr) * DMODEL + col] = (bf16_t)vv;
                else
                    ((float*)Cout)[(size_t)(rbase + rr) * DMODEL + col] = vv;
            }
        }
    }
}

// ---------------------------------------------------------------------------
// MFMA flash attention, 8 waves x 512 threads, QBLK=128 (16 q-rows/wave),
// KVBLK=64. Swapped QK^T + in-register base-2 softmax + defer-max.
// K double-buffered (gload_lds, prefetch 1 tile ahead, issued AFTER B1);
// V reg-staged 1 tile ahead (16B/thread); Vt single buffer; Ps barrier-free
// (wave w only touches Ps rows [16w,16w+16) -> lgkmcnt(0) suffices).
//
// Per iter t (b = t&1):
//  1. Vt write from vcur regs      (first vcur use -> compiler vmcnt wait
//                                   FIFO-drains the K(t) gload from iter t-1)
//  2. lgkmcnt(0); s_barrier  [B1]  (Vt + Ks[b] visible; vmem NOT drained)
//  3. prefetch: gload K(t+1)->Ks[b^1]; V(t+1)->vnxt   (Ks[b^1] readers all
//                                   finished before B1 -> no race)
//  4. QK^T from Ks[b]; softmax (in-register, defer-max)
//  5. Ps write; lgkmcnt(0); Ps read (same-wave rows only)
//  6. PV from Ps,Vt
//  7. lgkmcnt(0); s_barrier  [B2]  (PV reads done before next Vt overwrite)
// ---------------------------------------------------------------------------
__global__ __launch_bounds__(512) void flash_mfma(
    const bf16_t* __restrict__ qg, const bf16_t* __restrict__ kg,
    const bf16_t* __restrict__ vg, bf16_t* __restrict__ ctx)
{
    __shared__ bf16_t Ks[2][64 * 64];   // [key][dim], byte ^= (key&7)<<4
    __shared__ bf16_t Vt[64 * 72];      // [dim][key], padded pitch 72
    __shared__ bf16_t Ps[128 * 72];     // [q][key],  padded pitch 72

    const int t = threadIdx.x;
    const int w = t >> 6, lane = t & 63;
    const int r16 = lane & 15, g = lane >> 4;
    const int g4 = g * 4;
    const int q0 = blockIdx.x * 128, h = blockIdx.y, b = blockIdx.z;

    // Q fragments in registers: row = q0+16w+r16, k = kc*32 + g*8 + j
    bf16x8 qf0, qf1;
    {
        const bf16_t* qrow = qg + (size_t)(b * SEQ + q0 + 16 * w + r16) * DMODEL + h * DHEAD;
        qf0 = *(const bf16x8*)&qrow[g * 8];
        qf1 = *(const bf16x8*)&qrow[32 + g * 8];
    }

    // K staging: one gload_lds per wave: dest byte y = w*1024 + lane*16
    const int yk = w * 1024 + lane * 16;
    const int krow = yk >> 7;                       // 0..63 (8 rows per wave)
    const int kslot = ((yk >> 4) & 7) ^ (krow & 7); // pre-swizzled source col
    const bf16_t* kbase = kg + (size_t)(b * SEQ + krow) * DMODEL + h * DHEAD + kslot * 8;
    const int kdo = w * 512;                        // element offset in Ks[b]

    // V staging: thread loads key=lane, dims [w*8, w*8+8)  (16B)
    const bf16_t* vbase = vg + (size_t)(b * SEQ + lane) * DMODEL + h * DHEAD + w * 8;

    // K fragment base offsets (elements), swizzled; koff = base_kc + nj*1024
    const int klin0 = ((r16 * 128 + g * 16) ^ ((r16 & 7) << 4)) >> 1;
    const int klin1 = ((r16 * 128 + 64 + g * 16) ^ ((r16 & 7) << 4)) >> 1;

    const f32x4 z4 = {0.f, 0.f, 0.f, 0.f};
    // softmax state per lane: q-row = 16w + r16, base-2 domain
    float m2 = -1e30f, l2 = 0.f;
    f32x4 o_[4];                       // [d-block]; rows q = 16w + g4+rr
#pragma unroll
    for (int i = 0; i < 4; ++i) o_[i] = z4;

    const float C2 = 0.1803368801f;    // (1/8) * log2(e)
    const float THR2 = 11.5416f;       // 8 * log2(e)

    // ---- prologue: stage tile 0 (V load issued after K gload -> FIFO drain)
    gload_lds16(kbase, &Ks[0][kdo]);
    bf16x8 vcur = *(const bf16x8*)vbase;
    bf16x8 vnxt = vcur;

    const int NT = SEQ / 64;           // 32
    for (int it = 0; it < NT; ++it) {
        const int cur = it & 1;
        const int kv0 = it * 64;

        // 1. Vt write (vmcnt wait on vcur here drains K(t) gload too)
#pragma unroll
        for (int e = 0; e < 8; ++e)
            Vt[(w * 8 + e) * 72 + lane] = vcur[e];

        // 2. B1
        asm volatile("s_waitcnt lgkmcnt(0)" ::: "memory");
        __builtin_amdgcn_s_barrier();

        // 3. prefetch tile t+1 (stays in flight across compute)
        if (it + 1 < NT) {
            gload_lds16(kbase + (size_t)(kv0 + 64) * DMODEL, &Ks[cur ^ 1][kdo]);
            vnxt = *(const bf16x8*)(vbase + (size_t)(kv0 + 64) * DMODEL);
        }

        // 4. S^T = K Q^T : s[nj][rr] = S[key=nj*16+g4+rr][q=16w+r16]
        f32x4 s[4];
        __builtin_amdgcn_s_setprio(1);
#pragma unroll
        for (int nj = 0; nj < 4; ++nj) {
            bf16x8 kf0 = *(const bf16x8*)&Ks[cur][klin0 + nj * 1024];
            bf16x8 kf1 = *(const bf16x8*)&Ks[cur][klin1 + nj * 1024];
            s[nj] = __builtin_amdgcn_mfma_f32_16x16x32_bf16(kf0, qf0, z4, 0, 0, 0);
            s[nj] = __builtin_amdgcn_mfma_f32_16x16x32_bf16(kf1, qf1, s[nj], 0, 0, 0);
        }
        __builtin_amdgcn_s_setprio(0);

        // row max over this lane's 16 scores (one q-row) + reduce over g
        float mm[4];
#pragma unroll
        for (int nj = 0; nj < 4; ++nj)
            mm[nj] = fmaxf(fmaxf(s[nj][0], s[nj][1]), fmaxf(s[nj][2], s[nj][3]));
        float mx2 = fmaxf(fmaxf(mm[0], mm[1]), fmaxf(mm[2], mm[3])) * C2;
        mx2 = fmaxf(mx2, __shfl_xor(mx2, 16));
        mx2 = fmaxf(mx2, __shfl_xor(mx2, 32));

        // defer-max: rescale only when the max moved by > 8 (nat-log units)
        if (!__all(mx2 - m2 <= THR2)) {
            const float mnew = fmaxf(m2, mx2);
            const float fs = exp2f(m2 - mnew);
            m2 = mnew;
            l2 *= fs;
            const float f0 = __shfl(fs, g4 + 0, 16);
            const float f1 = __shfl(fs, g4 + 1, 16);
            const float f2 = __shfl(fs, g4 + 2, 16);
            const float f3 = __shfl(fs, g4 + 3, 16);
#pragma unroll
            for (int nj = 0; nj < 4; ++nj) {
                f32x4 t4 = o_[nj];
                t4[0] *= f0; t4[1] *= f1; t4[2] *= f2; t4[3] *= f3;
                o_[nj] = t4;
            }
        }

        // P = exp2(s*C2 - m2), row-sum in-register + 2 shfl
        float p[4][4];
        float rs = 0.f;
#pragma unroll
        for (int nj = 0; nj < 4; ++nj)
#pragma unroll
            for (int rr = 0; rr < 4; ++rr) {
                p[nj][rr] = exp2f(s[nj][rr] * C2 - m2);
                rs += p[nj][rr];
            }
        rs += __shfl_xor(rs, 16);
        rs += __shfl_xor(rs, 32);
        l2 += rs;

        // 5. Ps write (wave-local rows) + lgkm wait + read A-frags
#pragma unroll
        for (int nj = 0; nj < 4; ++nj) {
            bf16x4 pk;
            pk[0] = (bf16_t)p[nj][0]; pk[1] = (bf16_t)p[nj][1];
            pk[2] = (bf16_t)p[nj][2]; pk[3] = (bf16_t)p[nj][3];
            *(bf16x4*)&Ps[(16 * w + r16) * 72 + nj * 16 + g4] = pk;
        }
        asm volatile("s_waitcnt lgkmcnt(0)" ::: "memory");
        bf16x8 pf0 = *(const bf16x8*)&Ps[(16 * w + r16) * 72 + g * 8];
        bf16x8 pf1 = *(const bf16x8*)&Ps[(16 * w + r16) * 72 + 32 + g * 8];

        // 6. O += P V : B-frag from Vt
        __builtin_amdgcn_s_setprio(1);
#pragma unroll
        for (int dj = 0; dj < 4; ++dj) {
            bf16x8 vf0 = *(const bf16x8*)&Vt[(dj * 16 + r16) * 72 + g * 8];
            bf16x8 vf1 = *(const bf16x8*)&Vt[(dj * 16 + r16) * 72 + 32 + g * 8];
            o_[dj] = __builtin_amdgcn_mfma_f32_16x16x32_bf16(pf0, vf0, o_[dj], 0, 0, 0);
            o_[dj] = __builtin_amdgcn_mfma_f32_16x16x32_bf16(pf1, vf1, o_[dj], 0, 0, 0);
        }
        __builtin_amdgcn_s_setprio(0);

        // 7. B2 (raw barrier; vmem prefetch stays in flight)
        asm volatile("s_waitcnt lgkmcnt(0)" ::: "memory");
        __builtin_amdgcn_s_barrier();

        vcur = vnxt;
    }

    // write context (bf16): o_ rows are q = 16w+g4+rr; l lives at lane q=r16
#pragma unroll
    for (int rr = 0; rr < 4; ++rr) {
        const float lv = __shfl(l2, g4 + rr, 16);
        const float inv = 1.0f / lv;
        const size_t rowbase =
            (size_t)(b * SEQ + q0 + 16 * w + g4 + rr) * DMODEL + h * DHEAD;
#pragma unroll
        for (int dj = 0; dj < 4; ++dj)
            ctx[rowbase + dj * 16 + r16] = (bf16_t)(o_[dj][rr] * inv);
    }
}

// ---------------------------------------------------------------------------
// out = LayerNorm(x + res) * g + b, rows of 1024. One block per row.
// ---------------------------------------------------------------------------
__global__ __launch_bounds__(256) void ln_residual(
    const float* __restrict__ x, const float* __restrict__ res,
    const float* __restrict__ g, const float* __restrict__ bb,
    float* __restrict__ out)
{
    const int row = blockIdx.x;
    const int t = threadIdx.x;
    f4 xv = *(const f4*)&x[(size_t)row * DMODEL + t * 4];
    f4 rv = *(const f4*)&res[(size_t)row * DMODEL + t * 4];
    f4 v;
#pragma unroll
    for (int u = 0; u < 4; ++u) v[u] = xv[u] + rv[u];

    float s = 0.f, s2 = 0.f;
#pragma unroll
    for (int u = 0; u < 4; ++u) { s += v[u]; s2 += v[u] * v[u]; }
#pragma unroll
    for (int off = 1; off < 64; off <<= 1) {
        s  += __shfl_xor(s, off);
        s2 += __shfl_xor(s2, off);
    }
    __shared__ float red[2][4];
    const int wid = t >> 6, lane = t & 63;
    if (lane == 0) { red[0][wid] = s; red[1][wid] = s2; }
    __syncthreads();
    s  = red[0][0] + red[0][1] + red[0][2] + red[0][3];
    s2 = red[1][0] + red[1][1] + red[1][2] + red[1][3];

    const float mean = s * (1.0f / DMODEL);
    const float var  = s2 * (1.0f / DMODEL) - mean * mean;
    const float rstd = rsqrtf(var + LN_EPS);

    f4 gv = *(const f4*)&g[t * 4];
    f4 bv = *(const f4*)&bb[t * 4];
    f4 ov;
#pragma unroll
    for (int u = 0; u < 4; ++u) ov[u] = (v[u] - mean) * rstd * gv[u] + bv[u];
    *(f4*)&out[(size_t)row * DMODEL + t * 4] = ov;
}

// ---------------------------------------------------------------------------
extern "C" void kernel_launch(void* const* d_in, const int* in_sizes, int n_in,
                              void* d_out, int out_size, void* d_ws, size_t ws_size,
                              hipStream_t stream)
{
    const float* Q   = (const float*)d_in[0];
    const float* Wq  = (const float*)d_in[1];
    const float* bq  = (const float*)d_in[2];
    const float* Wk  = (const float*)d_in[3];
    const float* bk  = (const float*)d_in[4];
    const float* Wv  = (const float*)d_in[5];
    const float* bv  = (const float*)d_in[6];
    const float* Wo  = (const float*)d_in[7];
    const float* bo  = (const float*)d_in[8];
    const float* lng = (const float*)d_in[9];
    const float* lnb = (const float*)d_in[10];

    char* wsb = (char*)d_ws;
    // 0..16M: Qbf | 16..32M: q/ctx | 32..48M: k | 48..64M: v
    // 32..64M (after attn): attn_out fp32 | 64..72M: transposed bf16 weights
    bf16_t* Qbf  = (bf16_t*)(wsb);
    bf16_t* qb   = (bf16_t*)(wsb + (size_t)(16 << 20));
    bf16_t* kb   = (bf16_t*)(wsb + (size_t)(32 << 20));
    bf16_t* vbuf = (bf16_t*)(wsb + (size_t)(48 << 20));
    float*  ao   = (float*) (wsb + (size_t)(32 << 20));
    bf16_t* Wqt  = (bf16_t*)(wsb + (size_t)(64 << 20));
    bf16_t* Wkt  = (bf16_t*)(wsb + (size_t)(66 << 20));
    bf16_t* Wvt  = (bf16_t*)(wsb + (size_t)(68 << 20));
    bf16_t* Wot  = (bf16_t*)(wsb + (size_t)(70 << 20));

    cvt_bf16<<<2048, 256, 0, stream>>>(Q, Qbf, MTOT * DMODEL / 4);
    dim3 wg(32, 32);
    wtrans<<<wg, 256, 0, stream>>>(Wq, Wqt);
    wtrans<<<wg, 256, 0, stream>>>(Wk, Wkt);
    wtrans<<<wg, 256, 0, stream>>>(Wv, Wvt);
    wtrans<<<wg, 256, 0, stream>>>(Wo, Wot);

    dim3 gg(DMODEL / 128, MTOT / 128);            // (8, 64)
    gemm_mfma<1><<<gg, 256, 0, stream>>>(Qbf, Wqt, bq, qb);
    gemm_mfma<1><<<gg, 256, 0, stream>>>(Qbf, Wkt, bk, kb);
    gemm_mfma<1><<<gg, 256, 0, stream>>>(Qbf, Wvt, bv, vbuf);

    dim3 ga(SEQ / 128, NHEAD, BATCH);             // (16, 16, 4)
    flash_mfma<<<ga, 512, 0, stream>>>(qb, kb, vbuf, qb);  // ctx aliases q

    gemm_mfma<0><<<gg, 256, 0, stream>>>(qb, Wot, bo, ao);

    ln_residual<<<MTOT, 256, 0, stream>>>(ao, Q, lng, lnb, (float*)d_out);
}

// Round 7
// 266.729 us; speedup vs baseline: 1.2400x; 1.0620x over previous
//
#include <hip/hip_runtime.h>
#include <math.h>

#define BATCH 4
#define SEQ 2048
#define DMODEL 1024
#define NHEAD 16
#define DHEAD 64
#define MTOT (BATCH * SEQ)   /* 8192 */
#define LN_EPS 1e-5f

typedef float f4 __attribute__((ext_vector_type(4)));
typedef float f32x4 __attribute__((ext_vector_type(4)));
typedef __bf16 bf16_t;
typedef __bf16 bf16x8 __attribute__((ext_vector_type(8)));
typedef __bf16 bf16x4 __attribute__((ext_vector_type(4)));

// async global->LDS, 16B per lane; dest = wave-uniform base + lane*16
__device__ __forceinline__ void gload_lds16(const bf16_t* g, bf16_t* l) {
    __builtin_amdgcn_global_load_lds(
        (const __attribute__((address_space(1))) void*)g,
        (__attribute__((address_space(3))) void*)l, 16, 0, 0);
}

// ---------------------------------------------------------------------------
// fp32 -> bf16 elementwise (n4 = count of float4 groups)
// ---------------------------------------------------------------------------
__global__ __launch_bounds__(256) void cvt_bf16(
    const float* __restrict__ x, bf16_t* __restrict__ y, int n4)
{
    for (int i = blockIdx.x * 256 + threadIdx.x; i < n4; i += gridDim.x * 256) {
        f4 v = *(const f4*)&x[(size_t)i * 4];
        bf16x4 o;
        o[0] = (bf16_t)v[0]; o[1] = (bf16_t)v[1];
        o[2] = (bf16_t)v[2]; o[3] = (bf16_t)v[3];
        *(bf16x4*)&y[(size_t)i * 4] = o;
    }
}

// ---------------------------------------------------------------------------
// W[k][n] fp32 -> Wt[n][k] bf16 (32x32 LDS tiles)
// ---------------------------------------------------------------------------
__global__ __launch_bounds__(256) void wtrans(
    const float* __restrict__ W, bf16_t* __restrict__ Wt)
{
    __shared__ float tile[32][33];
    const int n0 = blockIdx.x * 32, k0 = blockIdx.y * 32;
    const int c = threadIdx.x & 31, rr = threadIdx.x >> 5;   // 8 rows/pass
#pragma unroll
    for (int i = 0; i < 32; i += 8)
        tile[rr + i][c] = W[(size_t)(k0 + rr + i) * DMODEL + n0 + c];
    __syncthreads();
#pragma unroll
    for (int i = 0; i < 32; i += 8)
        Wt[(size_t)(n0 + rr + i) * DMODEL + k0 + c] = (bf16_t)tile[c][rr + i];
}

// ---------------------------------------------------------------------------
// bf16 MFMA GEMM: C[M=8192][1024] = A[M][1024] @ Bt[n][k]^T + bias
// 128x128 tile, BK=32, 4 waves (2x2), 16x16x32 MFMA, global_load_lds(16B)
// LDS swizzle: byte ^= ((byte>>7)&3)<<4 (read side); source pre-swizzled.
// ---------------------------------------------------------------------------
template<int OUT_BF16>
__global__ __launch_bounds__(256) void gemm_mfma(
    const bf16_t* __restrict__ A, const bf16_t* __restrict__ Bt,
    const float* __restrict__ bias, void* __restrict__ Cout)
{
    __shared__ bf16_t As[128 * 32];
    __shared__ bf16_t Bs[128 * 32];
    const int t = threadIdx.x;
    const int w = t >> 6, lane = t & 63;
    const int r16 = lane & 15, g = lane >> 4;
    const int m0 = blockIdx.y * 128, n0 = blockIdx.x * 128;
    const int wr = w >> 1, wc = w & 1;

    // staging: issue r in {0,1}: dest byte y = r*4096 + w*1024 + lane*16
    const int y0 = w * 1024 + lane * 16;
    const int y1 = y0 + 4096;
    const int row0 = y0 >> 6, row1 = y1 >> 6;
    const int sl0 = ((y0 >> 4) & 3) ^ ((row0 >> 1) & 3);
    const int sl1 = ((y1 >> 4) & 3) ^ ((row1 >> 1) & 3);
    const bf16_t* a0 = A + (size_t)(m0 + row0) * DMODEL + sl0 * 8;
    const bf16_t* a1 = A + (size_t)(m0 + row1) * DMODEL + sl1 * 8;
    const bf16_t* b0 = Bt + (size_t)(n0 + row0) * DMODEL + sl0 * 8;
    const bf16_t* b1 = Bt + (size_t)(n0 + row1) * DMODEL + sl1 * 8;
    bf16_t* da0 = As + w * 512;
    bf16_t* da1 = As + 2048 + w * 512;
    bf16_t* db0 = Bs + w * 512;
    bf16_t* db1 = Bs + 2048 + w * 512;

    // fragment read offsets (elements), swizzled
    int aoff[4], boff[4];
#pragma unroll
    for (int i = 0; i < 4; ++i) {
        int ar = wr * 64 + i * 16 + r16;
        int al = ar * 64 + g * 16;
        al ^= ((ar >> 1) & 3) << 4;
        aoff[i] = al >> 1;
        int br = wc * 64 + i * 16 + r16;
        int bl = br * 64 + g * 16;
        bl ^= ((br >> 1) & 3) << 4;
        boff[i] = bl >> 1;
    }

    const f32x4 z4 = {0.f, 0.f, 0.f, 0.f};
    f32x4 acc[4][4];
#pragma unroll
    for (int i = 0; i < 4; ++i)
#pragma unroll
        for (int j = 0; j < 4; ++j) acc[i][j] = z4;

    for (int k0 = 0; k0 < DMODEL; k0 += 32) {
        __syncthreads();                 // prior LDS reads complete
        gload_lds16(a0 + k0, da0);
        gload_lds16(a1 + k0, da1);
        gload_lds16(b0 + k0, db0);
        gload_lds16(b1 + k0, db1);
        __syncthreads();                 // barrier drains vmcnt -> tiles ready
        bf16x8 af[4], bfr[4];
#pragma unroll
        for (int i = 0; i < 4; ++i) af[i] = *(const bf16x8*)&As[aoff[i]];
#pragma unroll
        for (int j = 0; j < 4; ++j) bfr[j] = *(const bf16x8*)&Bs[boff[j]];
#pragma unroll
        for (int i = 0; i < 4; ++i)
#pragma unroll
            for (int j = 0; j < 4; ++j)
                acc[i][j] = __builtin_amdgcn_mfma_f32_16x16x32_bf16(
                    af[i], bfr[j], acc[i][j], 0, 0, 0);
    }

    // epilogue: D row = (lane>>4)*4 + reg, col = lane&15  (m89-verified)
#pragma unroll
    for (int j = 0; j < 4; ++j) {
        const int col = n0 + wc * 64 + j * 16 + r16;
        const float bv = bias[col];
#pragma unroll
        for (int i = 0; i < 4; ++i) {
            const int rbase = m0 + wr * 64 + i * 16 + g * 4;
#pragma unroll
            for (int rr = 0; rr < 4; ++rr) {
                float vv = acc[i][j][rr] + bv;
                if (OUT_BF16)
                    ((bf16_t*)Cout)[(size_t)(rbase + rr) * DMODEL + col] = (bf16_t)vv;
                else
                    ((float*)Cout)[(size_t)(rbase + rr) * DMODEL + col] = vv;
            }
        }
    }
}

// ---------------------------------------------------------------------------
// MFMA flash attention, 8 waves x 512 threads, QBLK=128 (16 q-rows/wave),
// KVBLK=64. Swapped QK^T + in-register base-2 softmax + defer-max.
// K double-buffered (gload_lds, prefetch 1 tile ahead, issued AFTER B1);
// V reg-staged 1 tile ahead (16B/thread); Vt single buffer; Ps barrier-free
// (wave w only touches Ps rows [16w,16w+16) -> lgkmcnt(0) suffices).
// exp via __builtin_amdgcn_exp2f (raw v_exp_f32; libm exp2f is ~20 VALU ops).
//
// Per iter t (b = t&1):
//  1. Vt write from vcur regs      (first vcur use -> compiler vmcnt wait
//                                   FIFO-drains the K(t) gload from iter t-1)
//  2. lgkmcnt(0); s_barrier  [B1]  (Vt + Ks[b] visible; vmem NOT drained)
//  3. prefetch: gload K(t+1)->Ks[b^1]; V(t+1)->vnxt   (Ks[b^1] readers all
//                                   finished before B1 -> no race)
//  4. QK^T from Ks[b]; softmax (in-register, defer-max)
//  5. Ps write; lgkmcnt(0); Ps read (same-wave rows only)
//  6. PV from Ps,Vt
//  7. lgkmcnt(0); s_barrier  [B2]  (PV reads done before next Vt overwrite)
// ---------------------------------------------------------------------------
__global__ __launch_bounds__(512) void flash_mfma(
    const bf16_t* __restrict__ qg, const bf16_t* __restrict__ kg,
    const bf16_t* __restrict__ vg, bf16_t* __restrict__ ctx)
{
    __shared__ bf16_t Ks[2][64 * 64];   // [key][dim], byte ^= (key&7)<<4
    __shared__ bf16_t Vt[64 * 72];      // [dim][key], padded pitch 72
    __shared__ bf16_t Ps[128 * 72];     // [q][key],  padded pitch 72

    const int t = threadIdx.x;
    const int w = t >> 6, lane = t & 63;
    const int r16 = lane & 15, g = lane >> 4;
    const int g4 = g * 4;
    const int q0 = blockIdx.x * 128, h = blockIdx.y, b = blockIdx.z;

    // Q fragments in registers: row = q0+16w+r16, k = kc*32 + g*8 + j
    bf16x8 qf0, qf1;
    {
        const bf16_t* qrow = qg + (size_t)(b * SEQ + q0 + 16 * w + r16) * DMODEL + h * DHEAD;
        qf0 = *(const bf16x8*)&qrow[g * 8];
        qf1 = *(const bf16x8*)&qrow[32 + g * 8];
    }

    // K staging: one gload_lds per wave: dest byte y = w*1024 + lane*16
    const int yk = w * 1024 + lane * 16;
    const int krow = yk >> 7;                       // 0..63 (8 rows per wave)
    const int kslot = ((yk >> 4) & 7) ^ (krow & 7); // pre-swizzled source col
    const bf16_t* kbase = kg + (size_t)(b * SEQ + krow) * DMODEL + h * DHEAD + kslot * 8;
    const int kdo = w * 512;                        // element offset in Ks[b]

    // V staging: thread loads key=lane, dims [w*8, w*8+8)  (16B)
    const bf16_t* vbase = vg + (size_t)(b * SEQ + lane) * DMODEL + h * DHEAD + w * 8;

    // K fragment base offsets (elements), swizzled; koff = base_kc + nj*1024
    const int klin0 = ((r16 * 128 + g * 16) ^ ((r16 & 7) << 4)) >> 1;
    const int klin1 = ((r16 * 128 + 64 + g * 16) ^ ((r16 & 7) << 4)) >> 1;

    const f32x4 z4 = {0.f, 0.f, 0.f, 0.f};
    // softmax state per lane: q-row = 16w + r16, base-2 domain
    float m2 = -1e30f, l2 = 0.f;
    f32x4 o_[4];                       // [d-block]; rows q = 16w + g4+rr
#pragma unroll
    for (int i = 0; i < 4; ++i) o_[i] = z4;

    const float C2 = 0.1803368801f;    // (1/8) * log2(e)
    const float THR2 = 11.5416f;       // 8 * log2(e)

    // ---- prologue: stage tile 0 (V load issued after K gload -> FIFO drain)
    gload_lds16(kbase, &Ks[0][kdo]);
    bf16x8 vcur = *(const bf16x8*)vbase;
    bf16x8 vnxt = vcur;

    const int NT = SEQ / 64;           // 32
    for (int it = 0; it < NT; ++it) {
        const int cur = it & 1;
        const int kv0 = it * 64;

        // 1. Vt write (vmcnt wait on vcur here drains K(t) gload too)
#pragma unroll
        for (int e = 0; e < 8; ++e)
            Vt[(w * 8 + e) * 72 + lane] = vcur[e];

        // 2. B1
        asm volatile("s_waitcnt lgkmcnt(0)" ::: "memory");
        __builtin_amdgcn_s_barrier();

        // 3. prefetch tile t+1 (stays in flight across compute)
        if (it + 1 < NT) {
            gload_lds16(kbase + (size_t)(kv0 + 64) * DMODEL, &Ks[cur ^ 1][kdo]);
            vnxt = *(const bf16x8*)(vbase + (size_t)(kv0 + 64) * DMODEL);
        }

        // 4. S^T = K Q^T : s[nj][rr] = S[key=nj*16+g4+rr][q=16w+r16]
        f32x4 s[4];
        __builtin_amdgcn_s_setprio(1);
#pragma unroll
        for (int nj = 0; nj < 4; ++nj) {
            bf16x8 kf0 = *(const bf16x8*)&Ks[cur][klin0 + nj * 1024];
            bf16x8 kf1 = *(const bf16x8*)&Ks[cur][klin1 + nj * 1024];
            s[nj] = __builtin_amdgcn_mfma_f32_16x16x32_bf16(kf0, qf0, z4, 0, 0, 0);
            s[nj] = __builtin_amdgcn_mfma_f32_16x16x32_bf16(kf1, qf1, s[nj], 0, 0, 0);
        }
        __builtin_amdgcn_s_setprio(0);

        // row max over this lane's 16 scores (one q-row) + reduce over g
        float mm[4];
#pragma unroll
        for (int nj = 0; nj < 4; ++nj)
            mm[nj] = fmaxf(fmaxf(s[nj][0], s[nj][1]), fmaxf(s[nj][2], s[nj][3]));
        float mx2 = fmaxf(fmaxf(mm[0], mm[1]), fmaxf(mm[2], mm[3])) * C2;
        mx2 = fmaxf(mx2, __shfl_xor(mx2, 16));
        mx2 = fmaxf(mx2, __shfl_xor(mx2, 32));

        // defer-max: rescale only when the max moved by > 8 (nat-log units)
        if (!__all(mx2 - m2 <= THR2)) {
            const float mnew = fmaxf(m2, mx2);
            const float fs = __builtin_amdgcn_exp2f(m2 - mnew);
            m2 = mnew;
            l2 *= fs;
            const float f0 = __shfl(fs, g4 + 0, 16);
            const float f1 = __shfl(fs, g4 + 1, 16);
            const float f2 = __shfl(fs, g4 + 2, 16);
            const float f3 = __shfl(fs, g4 + 3, 16);
#pragma unroll
            for (int nj = 0; nj < 4; ++nj) {
                f32x4 t4 = o_[nj];
                t4[0] *= f0; t4[1] *= f1; t4[2] *= f2; t4[3] *= f3;
                o_[nj] = t4;
            }
        }

        // P = exp2(s*C2 - m2) via v_exp_f32, row-sum in-register + 2 shfl
        float p[4][4];
        float rs = 0.f;
#pragma unroll
        for (int nj = 0; nj < 4; ++nj)
#pragma unroll
            for (int rr = 0; rr < 4; ++rr) {
                p[nj][rr] = __builtin_amdgcn_exp2f(s[nj][rr] * C2 - m2);
                rs += p[nj][rr];
            }
        rs += __shfl_xor(rs, 16);
        rs += __shfl_xor(rs, 32);
        l2 += rs;

        // 5. Ps write (wave-local rows) + lgkm wait + read A-frags
#pragma unroll
        for (int nj = 0; nj < 4; ++nj) {
            bf16x4 pk;
            pk[0] = (bf16_t)p[nj][0]; pk[1] = (bf16_t)p[nj][1];
            pk[2] = (bf16_t)p[nj][2]; pk[3] = (bf16_t)p[nj][3];
            *(bf16x4*)&Ps[(16 * w + r16) * 72 + nj * 16 + g4] = pk;
        }
        asm volatile("s_waitcnt lgkmcnt(0)" ::: "memory");
        bf16x8 pf0 = *(const bf16x8*)&Ps[(16 * w + r16) * 72 + g * 8];
        bf16x8 pf1 = *(const bf16x8*)&Ps[(16 * w + r16) * 72 + 32 + g * 8];

        // 6. O += P V : B-frag from Vt
        __builtin_amdgcn_s_setprio(1);
#pragma unroll
        for (int dj = 0; dj < 4; ++dj) {
            bf16x8 vf0 = *(const bf16x8*)&Vt[(dj * 16 + r16) * 72 + g * 8];
            bf16x8 vf1 = *(const bf16x8*)&Vt[(dj * 16 + r16) * 72 + 32 + g * 8];
            o_[dj] = __builtin_amdgcn_mfma_f32_16x16x32_bf16(pf0, vf0, o_[dj], 0, 0, 0);
            o_[dj] = __builtin_amdgcn_mfma_f32_16x16x32_bf16(pf1, vf1, o_[dj], 0, 0, 0);
        }
        __builtin_amdgcn_s_setprio(0);

        // 7. B2 (raw barrier; vmem prefetch stays in flight)
        asm volatile("s_waitcnt lgkmcnt(0)" ::: "memory");
        __builtin_amdgcn_s_barrier();

        vcur = vnxt;
    }

    // write context (bf16): o_ rows are q = 16w+g4+rr; l lives at lane q=r16
#pragma unroll
    for (int rr = 0; rr < 4; ++rr) {
        const float lv = __shfl(l2, g4 + rr, 16);
        const float inv = 1.0f / lv;
        const size_t rowbase =
            (size_t)(b * SEQ + q0 + 16 * w + g4 + rr) * DMODEL + h * DHEAD;
#pragma unroll
        for (int dj = 0; dj < 4; ++dj)
            ctx[rowbase + dj * 16 + r16] = (bf16_t)(o_[dj][rr] * inv);
    }
}

// ---------------------------------------------------------------------------
// out = LayerNorm(x + res) * g + b, rows of 1024. One block per row.
// ---------------------------------------------------------------------------
__global__ __launch_bounds__(256) void ln_residual(
    const float* __restrict__ x, const float* __restrict__ res,
    const float* __restrict__ g, const float* __restrict__ bb,
    float* __restrict__ out)
{
    const int row = blockIdx.x;
    const int t = threadIdx.x;
    f4 xv = *(const f4*)&x[(size_t)row * DMODEL + t * 4];
    f4 rv = *(const f4*)&res[(size_t)row * DMODEL + t * 4];
    f4 v;
#pragma unroll
    for (int u = 0; u < 4; ++u) v[u] = xv[u] + rv[u];

    float s = 0.f, s2 = 0.f;
#pragma unroll
    for (int u = 0; u < 4; ++u) { s += v[u]; s2 += v[u] * v[u]; }
#pragma unroll
    for (int off = 1; off < 64; off <<= 1) {
        s  += __shfl_xor(s, off);
        s2 += __shfl_xor(s2, off);
    }
    __shared__ float red[2][4];
    const int wid = t >> 6, lane = t & 63;
    if (lane == 0) { red[0][wid] = s; red[1][wid] = s2; }
    __syncthreads();
    s  = red[0][0] + red[0][1] + red[0][2] + red[0][3];
    s2 = red[1][0] + red[1][1] + red[1][2] + red[1][3];

    const float mean = s * (1.0f / DMODEL);
    const float var  = s2 * (1.0f / DMODEL) - mean * mean;
    const float rstd = rsqrtf(var + LN_EPS);

    f4 gv = *(const f4*)&g[t * 4];
    f4 bv = *(const f4*)&bb[t * 4];
    f4 ov;
#pragma unroll
    for (int u = 0; u < 4; ++u) ov[u] = (v[u] - mean) * rstd * gv[u] + bv[u];
    *(f4*)&out[(size_t)row * DMODEL + t * 4] = ov;
}

// ---------------------------------------------------------------------------
extern "C" void kernel_launch(void* const* d_in, const int* in_sizes, int n_in,
                              void* d_out, int out_size, void* d_ws, size_t ws_size,
                              hipStream_t stream)
{
    const float* Q   = (const float*)d_in[0];
    const float* Wq  = (const float*)d_in[1];
    const float* bq  = (const float*)d_in[2];
    const float* Wk  = (const float*)d_in[3];
    const float* bk  = (const float*)d_in[4];
    const float* Wv  = (const float*)d_in[5];
    const float* bv  = (const float*)d_in[6];
    const float* Wo  = (const float*)d_in[7];
    const float* bo  = (const float*)d_in[8];
    const float* lng = (const float*)d_in[9];
    const float* lnb = (const float*)d_in[10];

    char* wsb = (char*)d_ws;
    // 0..16M: Qbf | 16..32M: q/ctx | 32..48M: k | 48..64M: v
    // 32..64M (after attn): attn_out fp32 | 64..72M: transposed bf16 weights
    bf16_t* Qbf  = (bf16_t*)(wsb);
    bf16_t* qb   = (bf16_t*)(wsb + (size_t)(16 << 20));
    bf16_t* kb   = (bf16_t*)(wsb + (size_t)(32 << 20));
    bf16_t* vbuf = (bf16_t*)(wsb + (size_t)(48 << 20));
    float*  ao   = (float*) (wsb + (size_t)(32 << 20));
    bf16_t* Wqt  = (bf16_t*)(wsb + (size_t)(64 << 20));
    bf16_t* Wkt  = (bf16_t*)(wsb + (size_t)(66 << 20));
    bf16_t* Wvt  = (bf16_t*)(wsb + (size_t)(68 << 20));
    bf16_t* Wot  = (bf16_t*)(wsb + (size_t)(70 << 20));

    cvt_bf16<<<2048, 256, 0, stream>>>(Q, Qbf, MTOT * DMODEL / 4);
    dim3 wg(32, 32);
    wtrans<<<wg, 256, 0, stream>>>(Wq, Wqt);
    wtrans<<<wg, 256, 0, stream>>>(Wk, Wkt);
    wtrans<<<wg, 256, 0, stream>>>(Wv, Wvt);
    wtrans<<<wg, 256, 0, stream>>>(Wo, Wot);

    dim3 gg(DMODEL / 128, MTOT / 128);            // (8, 64)
    gemm_mfma<1><<<gg, 256, 0, stream>>>(Qbf, Wqt, bq, qb);
    gemm_mfma<1><<<gg, 256, 0, stream>>>(Qbf, Wkt, bk, kb);
    gemm_mfma<1><<<gg, 256, 0, stream>>>(Qbf, Wvt, bv, vbuf);

    dim3 ga(SEQ / 128, NHEAD, BATCH);             // (16, 16, 4)
    flash_mfma<<<ga, 512, 0, stream>>>(qb, kb, vbuf, qb);  // ctx aliases q

    gemm_mfma<0><<<gg, 256, 0, stream>>>(qb, Wot, bo, ao);

    ln_residual<<<MTOT, 256, 0, stream>>>(ao, Q, lng, lnb, (float*)d_out);
}

// Round 8
// 250.550 us; speedup vs baseline: 1.3201x; 1.0646x over previous
//
#include <hip/hip_runtime.h>
#include <math.h>

#define BATCH 4
#define SEQ 2048
#define DMODEL 1024
#define NHEAD 16
#define DHEAD 64
#define MTOT (BATCH * SEQ)   /* 8192 */
#define LN_EPS 1e-5f

typedef float f4 __attribute__((ext_vector_type(4)));
typedef float f32x4 __attribute__((ext_vector_type(4)));
typedef __bf16 bf16_t;
typedef __bf16 bf16x8 __attribute__((ext_vector_type(8)));
typedef __bf16 bf16x4 __attribute__((ext_vector_type(4)));

// async global->LDS, 16B per lane; dest = wave-uniform base + lane*16
__device__ __forceinline__ void gload_lds16(const bf16_t* g, bf16_t* l) {
    __builtin_amdgcn_global_load_lds(
        (const __attribute__((address_space(1))) void*)g,
        (__attribute__((address_space(3))) void*)l, 16, 0, 0);
}

// ---------------------------------------------------------------------------
// fp32 -> bf16 elementwise (n4 = count of float4 groups)
// ---------------------------------------------------------------------------
__global__ __launch_bounds__(256) void cvt_bf16(
    const float* __restrict__ x, bf16_t* __restrict__ y, int n4)
{
    for (int i = blockIdx.x * 256 + threadIdx.x; i < n4; i += gridDim.x * 256) {
        f4 v = *(const f4*)&x[(size_t)i * 4];
        bf16x4 o;
        o[0] = (bf16_t)v[0]; o[1] = (bf16_t)v[1];
        o[2] = (bf16_t)v[2]; o[3] = (bf16_t)v[3];
        *(bf16x4*)&y[(size_t)i * 4] = o;
    }
}

// ---------------------------------------------------------------------------
// W[k][n] fp32 -> Wt[n][k] bf16 (32x32 LDS tiles)
// ---------------------------------------------------------------------------
__global__ __launch_bounds__(256) void wtrans(
    const float* __restrict__ W, bf16_t* __restrict__ Wt)
{
    __shared__ float tile[32][33];
    const int n0 = blockIdx.x * 32, k0 = blockIdx.y * 32;
    const int c = threadIdx.x & 31, rr = threadIdx.x >> 5;   // 8 rows/pass
#pragma unroll
    for (int i = 0; i < 32; i += 8)
        tile[rr + i][c] = W[(size_t)(k0 + rr + i) * DMODEL + n0 + c];
    __syncthreads();
#pragma unroll
    for (int i = 0; i < 32; i += 8)
        Wt[(size_t)(n0 + rr + i) * DMODEL + k0 + c] = (bf16_t)tile[c][rr + i];
}

// ---------------------------------------------------------------------------
// bf16 MFMA GEMM: C[M=8192][1024] = A[M][1024] @ Bt[n][k]^T + bias
// 128x128 tile, BK=32, 4 waves (2x2), 16x16x32 MFMA, global_load_lds(16B)
// LDS swizzle: byte ^= ((byte>>7)&3)<<4 (read side); source pre-swizzled.
// 1D grid (512) with XCD swizzle: xcd c <- contiguous 8 m-tiles x all n-tiles
// (per-XCD L2 working set = 2MB A-chunk + 2MB B = fits 4MB L2).
// ---------------------------------------------------------------------------
template<int OUT_BF16>
__global__ __launch_bounds__(256) void gemm_mfma(
    const bf16_t* __restrict__ A, const bf16_t* __restrict__ Bt,
    const float* __restrict__ bias, void* __restrict__ Cout)
{
    __shared__ bf16_t As[128 * 32];
    __shared__ bf16_t Bs[128 * 32];
    const int t = threadIdx.x;
    const int w = t >> 6, lane = t & 63;
    const int r16 = lane & 15, g = lane >> 4;

    // XCD swizzle: flat = c + 8*nx + 64*u ; my = 8c+u (c = my>>3 = XCD)
    const int flat = blockIdx.x;
    const int xc  = flat & 7;
    const int t2  = flat >> 3;
    const int nx  = t2 & 7;
    const int my  = 8 * xc + (t2 >> 3);
    const int m0 = my * 128, n0 = nx * 128;
    const int wr = w >> 1, wc = w & 1;

    // staging: issue r in {0,1}: dest byte y = r*4096 + w*1024 + lane*16
    const int y0 = w * 1024 + lane * 16;
    const int y1 = y0 + 4096;
    const int row0 = y0 >> 6, row1 = y1 >> 6;
    const int sl0 = ((y0 >> 4) & 3) ^ ((row0 >> 1) & 3);
    const int sl1 = ((y1 >> 4) & 3) ^ ((row1 >> 1) & 3);
    const bf16_t* a0 = A + (size_t)(m0 + row0) * DMODEL + sl0 * 8;
    const bf16_t* a1 = A + (size_t)(m0 + row1) * DMODEL + sl1 * 8;
    const bf16_t* b0 = Bt + (size_t)(n0 + row0) * DMODEL + sl0 * 8;
    const bf16_t* b1 = Bt + (size_t)(n0 + row1) * DMODEL + sl1 * 8;
    bf16_t* da0 = As + w * 512;
    bf16_t* da1 = As + 2048 + w * 512;
    bf16_t* db0 = Bs + w * 512;
    bf16_t* db1 = Bs + 2048 + w * 512;

    // fragment read offsets (elements), swizzled
    int aoff[4], boff[4];
#pragma unroll
    for (int i = 0; i < 4; ++i) {
        int ar = wr * 64 + i * 16 + r16;
        int al = ar * 64 + g * 16;
        al ^= ((ar >> 1) & 3) << 4;
        aoff[i] = al >> 1;
        int br = wc * 64 + i * 16 + r16;
        int bl = br * 64 + g * 16;
        bl ^= ((br >> 1) & 3) << 4;
        boff[i] = bl >> 1;
    }

    const f32x4 z4 = {0.f, 0.f, 0.f, 0.f};
    f32x4 acc[4][4];
#pragma unroll
    for (int i = 0; i < 4; ++i)
#pragma unroll
        for (int j = 0; j < 4; ++j) acc[i][j] = z4;

    for (int k0 = 0; k0 < DMODEL; k0 += 32) {
        __syncthreads();                 // prior LDS reads complete
        gload_lds16(a0 + k0, da0);
        gload_lds16(a1 + k0, da1);
        gload_lds16(b0 + k0, db0);
        gload_lds16(b1 + k0, db1);
        __syncthreads();                 // barrier drains vmcnt -> tiles ready
        bf16x8 af[4], bfr[4];
#pragma unroll
        for (int i = 0; i < 4; ++i) af[i] = *(const bf16x8*)&As[aoff[i]];
#pragma unroll
        for (int j = 0; j < 4; ++j) bfr[j] = *(const bf16x8*)&Bs[boff[j]];
#pragma unroll
        for (int i = 0; i < 4; ++i)
#pragma unroll
            for (int j = 0; j < 4; ++j)
                acc[i][j] = __builtin_amdgcn_mfma_f32_16x16x32_bf16(
                    af[i], bfr[j], acc[i][j], 0, 0, 0);
    }

    // epilogue: D row = (lane>>4)*4 + reg, col = lane&15  (m89-verified)
#pragma unroll
    for (int j = 0; j < 4; ++j) {
        const int col = n0 + wc * 64 + j * 16 + r16;
        const float bv = bias[col];
#pragma unroll
        for (int i = 0; i < 4; ++i) {
            const int rbase = m0 + wr * 64 + i * 16 + g * 4;
#pragma unroll
            for (int rr = 0; rr < 4; ++rr) {
                float vv = acc[i][j][rr] + bv;
                if (OUT_BF16)
                    ((bf16_t*)Cout)[(size_t)(rbase + rr) * DMODEL + col] = (bf16_t)vv;
                else
                    ((float*)Cout)[(size_t)(rbase + rr) * DMODEL + col] = vv;
            }
        }
    }
}

// ---------------------------------------------------------------------------
// MFMA flash attention, 8 waves x 512 threads, QBLK=128, KVBLK=64.
// LDS exactly 40960B (Ks 16K dbuf + Vt 8K swz + Ps 16K swz) -> 4 blocks/CU
// (exact fit: 4x512 thr = 2048, 4x40K = 160K), grid 1024 = exactly one
// residency round (no tail). XCD swizzle: all 16 q-tiles of one (b,h) on one
// XCD -> K/V L2-resident (8 groups x 512KB = 4MB/XCD).
// Vt/Ps swizzle: 16B-unit index (col>>3) XOR'd with (row&7), write and read.
// ---------------------------------------------------------------------------
__global__ __launch_bounds__(512) void flash_mfma(
    const bf16_t* __restrict__ qg, const bf16_t* __restrict__ kg,
    const bf16_t* __restrict__ vg, bf16_t* __restrict__ ctx)
{
    __shared__ bf16_t Ks[2][64 * 64];   // [key][dim], byte ^= (key&7)<<4
    __shared__ bf16_t Vt[64 * 64];      // [dim][key], unit ^= dim&7
    __shared__ bf16_t Ps[128 * 64];     // [q][key],   unit ^= q&7

    const int t = threadIdx.x;
    const int w = t >> 6, lane = t & 63;
    const int r16 = lane & 15, g = lane >> 4;
    const int g4 = g * 4;

    // XCD swizzle: flat = xc + 8*(qt + 16*(gid>>3)); gid&7 = xc
    const int flat = blockIdx.x;
    const int xc  = flat & 7;
    const int kk  = flat >> 3;                  // 0..127
    const int gid = ((kk >> 4) << 3) | xc;      // 0..63 = (b,h)
    const int qt  = kk & 15;
    const int b = gid >> 4, h = gid & 15;
    const int q0 = qt * 128;

    // Q fragments in registers: row = q0+16w+r16, k = kc*32 + g*8 + j
    bf16x8 qf0, qf1;
    {
        const bf16_t* qrow = qg + (size_t)(b * SEQ + q0 + 16 * w + r16) * DMODEL + h * DHEAD;
        qf0 = *(const bf16x8*)&qrow[g * 8];
        qf1 = *(const bf16x8*)&qrow[32 + g * 8];
    }

    // K staging: one gload_lds per wave: dest byte y = w*1024 + lane*16
    const int yk = w * 1024 + lane * 16;
    const int krow = yk >> 7;                       // 0..63 (8 rows per wave)
    const int kslot = ((yk >> 4) & 7) ^ (krow & 7); // pre-swizzled source col
    const bf16_t* kbase = kg + (size_t)(b * SEQ + krow) * DMODEL + h * DHEAD + kslot * 8;
    const int kdo = w * 512;                        // element offset in Ks[b]

    // V staging: thread loads key=lane, dims [w*8, w*8+8)  (16B)
    const bf16_t* vbase = vg + (size_t)(b * SEQ + lane) * DMODEL + h * DHEAD + w * 8;

    // K fragment base offsets (elements), swizzled; koff = base_kc + nj*1024
    const int klin0 = ((r16 * 128 + g * 16) ^ ((r16 & 7) << 4)) >> 1;
    const int klin1 = ((r16 * 128 + 64 + g * 16) ^ ((r16 & 7) << 4)) >> 1;

    // Vt/Ps swizzle constants
    const int lu = lane >> 3, l7 = lane & 7;   // V-write unit/offset
    const int qs = r16 & 7;                    // row&7 for q=16w+r16 and d=dj*16+r16

    const f32x4 z4 = {0.f, 0.f, 0.f, 0.f};
    // softmax state per lane: q-row = 16w + r16, base-2 domain
    float m2 = -1e30f, l2 = 0.f;
    f32x4 o_[4];                       // [d-block]; rows q = 16w + g4+rr
#pragma unroll
    for (int i = 0; i < 4; ++i) o_[i] = z4;

    const float C2 = 0.1803368801f;    // (1/8) * log2(e)
    const float THR2 = 11.5416f;       // 8 * log2(e)

    // ---- prologue: stage tile 0 (V load issued after K gload -> FIFO drain)
    gload_lds16(kbase, &Ks[0][kdo]);
    bf16x8 vcur = *(const bf16x8*)vbase;
    bf16x8 vnxt = vcur;

    const int NT = SEQ / 64;           // 32
    for (int it = 0; it < NT; ++it) {
        const int cur = it & 1;
        const int kv0 = it * 64;

        // 1. Vt write (vmcnt wait on vcur here drains K(t) gload too)
        //    d = w*8+e, key = lane; unit = (lane>>3)^e, offset lane&7
#pragma unroll
        for (int e = 0; e < 8; ++e)
            Vt[(w * 8 + e) * 64 + (((lu ^ e) << 3) | l7)] = vcur[e];

        // 2. B1
        asm volatile("s_waitcnt lgkmcnt(0)" ::: "memory");
        __builtin_amdgcn_s_barrier();

        // 3. prefetch tile t+1 (stays in flight across compute)
        if (it + 1 < NT) {
            gload_lds16(kbase + (size_t)(kv0 + 64) * DMODEL, &Ks[cur ^ 1][kdo]);
            vnxt = *(const bf16x8*)(vbase + (size_t)(kv0 + 64) * DMODEL);
        }

        // 4. S^T = K Q^T : s[nj][rr] = S[key=nj*16+g4+rr][q=16w+r16]
        f32x4 s[4];
        __builtin_amdgcn_s_setprio(1);
#pragma unroll
        for (int nj = 0; nj < 4; ++nj) {
            bf16x8 kf0 = *(const bf16x8*)&Ks[cur][klin0 + nj * 1024];
            bf16x8 kf1 = *(const bf16x8*)&Ks[cur][klin1 + nj * 1024];
            s[nj] = __builtin_amdgcn_mfma_f32_16x16x32_bf16(kf0, qf0, z4, 0, 0, 0);
            s[nj] = __builtin_amdgcn_mfma_f32_16x16x32_bf16(kf1, qf1, s[nj], 0, 0, 0);
        }
        __builtin_amdgcn_s_setprio(0);

        // row max over this lane's 16 scores (one q-row) + reduce over g
        float mm[4];
#pragma unroll
        for (int nj = 0; nj < 4; ++nj)
            mm[nj] = fmaxf(fmaxf(s[nj][0], s[nj][1]), fmaxf(s[nj][2], s[nj][3]));
        float mx2 = fmaxf(fmaxf(mm[0], mm[1]), fmaxf(mm[2], mm[3])) * C2;
        mx2 = fmaxf(mx2, __shfl_xor(mx2, 16));
        mx2 = fmaxf(mx2, __shfl_xor(mx2, 32));

        // defer-max: rescale only when the max moved by > 8 (nat-log units)
        if (!__all(mx2 - m2 <= THR2)) {
            const float mnew = fmaxf(m2, mx2);
            const float fs = __builtin_amdgcn_exp2f(m2 - mnew);
            m2 = mnew;
            l2 *= fs;
            const float f0 = __shfl(fs, g4 + 0, 16);
            const float f1 = __shfl(fs, g4 + 1, 16);
            const float f2 = __shfl(fs, g4 + 2, 16);
            const float f3 = __shfl(fs, g4 + 3, 16);
#pragma unroll
            for (int nj = 0; nj < 4; ++nj) {
                f32x4 t4 = o_[nj];
                t4[0] *= f0; t4[1] *= f1; t4[2] *= f2; t4[3] *= f3;
                o_[nj] = t4;
            }
        }

        // P = exp2(s*C2 - m2) via v_exp_f32, row-sum in-register + 2 shfl
        float p[4][4];
        float rs = 0.f;
#pragma unroll
        for (int nj = 0; nj < 4; ++nj)
#pragma unroll
            for (int rr = 0; rr < 4; ++rr) {
                p[nj][rr] = __builtin_amdgcn_exp2f(s[nj][rr] * C2 - m2);
                rs += p[nj][rr];
            }
        rs += __shfl_xor(rs, 16);
        rs += __shfl_xor(rs, 32);
        l2 += rs;

        // 5. Ps write (wave-local rows; swizzled unit = (2nj+(g>>1))^qs)
        const int qrow = 16 * w + r16;
#pragma unroll
        for (int nj = 0; nj < 4; ++nj) {
            bf16x4 pk;
            pk[0] = (bf16_t)p[nj][0]; pk[1] = (bf16_t)p[nj][1];
            pk[2] = (bf16_t)p[nj][2]; pk[3] = (bf16_t)p[nj][3];
            *(bf16x4*)&Ps[qrow * 64 + ((((2 * nj + (g >> 1)) ^ qs) << 3) | ((g & 1) << 2))] = pk;
        }
        asm volatile("s_waitcnt lgkmcnt(0)" ::: "memory");
        bf16x8 pf0 = *(const bf16x8*)&Ps[qrow * 64 + ((g ^ qs) << 3)];
        bf16x8 pf1 = *(const bf16x8*)&Ps[qrow * 64 + (((4 + g) ^ qs) << 3)];

        // 6. O += P V : B-frag from Vt (swizzled: unit = (h4+g)^(d&7))
        __builtin_amdgcn_s_setprio(1);
#pragma unroll
        for (int dj = 0; dj < 4; ++dj) {
            const int d = dj * 16 + r16;
            bf16x8 vf0 = *(const bf16x8*)&Vt[d * 64 + ((g ^ qs) << 3)];
            bf16x8 vf1 = *(const bf16x8*)&Vt[d * 64 + (((4 + g) ^ qs) << 3)];
            o_[dj] = __builtin_amdgcn_mfma_f32_16x16x32_bf16(pf0, vf0, o_[dj], 0, 0, 0);
            o_[dj] = __builtin_amdgcn_mfma_f32_16x16x32_bf16(pf1, vf1, o_[dj], 0, 0, 0);
        }
        __builtin_amdgcn_s_setprio(0);

        // 7. B2 (raw barrier; vmem prefetch stays in flight)
        asm volatile("s_waitcnt lgkmcnt(0)" ::: "memory");
        __builtin_amdgcn_s_barrier();

        vcur = vnxt;
    }

    // write context (bf16): o_ rows are q = 16w+g4+rr; l lives at lane q=r16
#pragma unroll
    for (int rr = 0; rr < 4; ++rr) {
        const float lv = __shfl(l2, g4 + rr, 16);
        const float inv = 1.0f / lv;
        const size_t rowbase =
            (size_t)(b * SEQ + q0 + 16 * w + g4 + rr) * DMODEL + h * DHEAD;
#pragma unroll
        for (int dj = 0; dj < 4; ++dj)
            ctx[rowbase + dj * 16 + r16] = (bf16_t)(o_[dj][rr] * inv);
    }
}

// ---------------------------------------------------------------------------
// out = LayerNorm(x + res) * g + b, rows of 1024. One block per row.
// ---------------------------------------------------------------------------
__global__ __launch_bounds__(256) void ln_residual(
    const float* __restrict__ x, const float* __restrict__ res,
    const float* __restrict__ g, const float* __restrict__ bb,
    float* __restrict__ out)
{
    const int row = blockIdx.x;
    const int t = threadIdx.x;
    f4 xv = *(const f4*)&x[(size_t)row * DMODEL + t * 4];
    f4 rv = *(const f4*)&res[(size_t)row * DMODEL + t * 4];
    f4 v;
#pragma unroll
    for (int u = 0; u < 4; ++u) v[u] = xv[u] + rv[u];

    float s = 0.f, s2 = 0.f;
#pragma unroll
    for (int u = 0; u < 4; ++u) { s += v[u]; s2 += v[u] * v[u]; }
#pragma unroll
    for (int off = 1; off < 64; off <<= 1) {
        s  += __shfl_xor(s, off);
        s2 += __shfl_xor(s2, off);
    }
    __shared__ float red[2][4];
    const int wid = t >> 6, lane = t & 63;
    if (lane == 0) { red[0][wid] = s; red[1][wid] = s2; }
    __syncthreads();
    s  = red[0][0] + red[0][1] + red[0][2] + red[0][3];
    s2 = red[1][0] + red[1][1] + red[1][2] + red[1][3];

    const float mean = s * (1.0f / DMODEL);
    const float var  = s2 * (1.0f / DMODEL) - mean * mean;
    const float rstd = rsqrtf(var + LN_EPS);

    f4 gv = *(const f4*)&g[t * 4];
    f4 bv = *(const f4*)&bb[t * 4];
    f4 ov;
#pragma unroll
    for (int u = 0; u < 4; ++u) ov[u] = (v[u] - mean) * rstd * gv[u] + bv[u];
    *(f4*)&out[(size_t)row * DMODEL + t * 4] = ov;
}

// ---------------------------------------------------------------------------
extern "C" void kernel_launch(void* const* d_in, const int* in_sizes, int n_in,
                              void* d_out, int out_size, void* d_ws, size_t ws_size,
                              hipStream_t stream)
{
    const float* Q   = (const float*)d_in[0];
    const float* Wq  = (const float*)d_in[1];
    const float* bq  = (const float*)d_in[2];
    const float* Wk  = (const float*)d_in[3];
    const float* bk  = (const float*)d_in[4];
    const float* Wv  = (const float*)d_in[5];
    const float* bv  = (const float*)d_in[6];
    const float* Wo  = (const float*)d_in[7];
    const float* bo  = (const float*)d_in[8];
    const float* lng = (const float*)d_in[9];
    const float* lnb = (const float*)d_in[10];

    char* wsb = (char*)d_ws;
    // 0..16M: Qbf | 16..32M: q/ctx | 32..48M: k | 48..64M: v
    // 32..64M (after attn): attn_out fp32 | 64..72M: transposed bf16 weights
    bf16_t* Qbf  = (bf16_t*)(wsb);
    bf16_t* qb   = (bf16_t*)(wsb + (size_t)(16 << 20));
    bf16_t* kb   = (bf16_t*)(wsb + (size_t)(32 << 20));
    bf16_t* vbuf = (bf16_t*)(wsb + (size_t)(48 << 20));
    float*  ao   = (float*) (wsb + (size_t)(32 << 20));
    bf16_t* Wqt  = (bf16_t*)(wsb + (size_t)(64 << 20));
    bf16_t* Wkt  = (bf16_t*)(wsb + (size_t)(66 << 20));
    bf16_t* Wvt  = (bf16_t*)(wsb + (size_t)(68 << 20));
    bf16_t* Wot  = (bf16_t*)(wsb + (size_t)(70 << 20));

    cvt_bf16<<<2048, 256, 0, stream>>>(Q, Qbf, MTOT * DMODEL / 4);
    dim3 wg(32, 32);
    wtrans<<<wg, 256, 0, stream>>>(Wq, Wqt);
    wtrans<<<wg, 256, 0, stream>>>(Wk, Wkt);
    wtrans<<<wg, 256, 0, stream>>>(Wv, Wvt);
    wtrans<<<wg, 256, 0, stream>>>(Wo, Wot);

    const int ggrid = (DMODEL / 128) * (MTOT / 128);   // 512, XCD-swizzled
    gemm_mfma<1><<<ggrid, 256, 0, stream>>>(Qbf, Wqt, bq, qb);
    gemm_mfma<1><<<ggrid, 256, 0, stream>>>(Qbf, Wkt, bk, kb);
    gemm_mfma<1><<<ggrid, 256, 0, stream>>>(Qbf, Wvt, bv, vbuf);

    const int agrid = (SEQ / 128) * NHEAD * BATCH;     // 1024, XCD-swizzled
    flash_mfma<<<agrid, 512, 0, stream>>>(qb, kb, vbuf, qb);  // ctx aliases q

    gemm_mfma<0><<<ggrid, 256, 0, stream>>>(qb, Wot, bo, ao);

    ln_residual<<<MTOT, 256, 0, stream>>>(ao, Q, lng, lnb, (float*)d_out);
}